// Round 1
// baseline (2040.777 us; speedup 1.0000x reference)
//
#include <hip/hip_runtime.h>
#include <math.h>

#define F 128
#define HEADS 8

// ---------------- CSR build ----------------

__global__ __launch_bounds__(256) void hist_k(const int* __restrict__ dst, int E, int* __restrict__ deg) {
    int e = blockIdx.x * 256 + threadIdx.x;
    if (e < E) atomicAdd(&deg[dst[e]], 1);
}

__global__ __launch_bounds__(256) void scan1_k(const int* __restrict__ deg, int N,
                                               int* __restrict__ start, int* __restrict__ partials) {
    __shared__ int sm[256];
    int t = threadIdx.x;
    int i = blockIdx.x * 256 + t;
    int v = (i < N) ? deg[i] : 0;
    sm[t] = v;
    __syncthreads();
    for (int off = 1; off < 256; off <<= 1) {
        int add = (t >= off) ? sm[t - off] : 0;
        __syncthreads();
        sm[t] += add;
        __syncthreads();
    }
    if (i < N) start[i] = sm[t] - v;  // exclusive within block
    if (t == 255) partials[blockIdx.x] = sm[t];
}

__global__ __launch_bounds__(256) void scan2_k(int* __restrict__ partials, int nb,
                                               int* __restrict__ start, int N, int E) {
    __shared__ int sm[256];
    int t = threadIdx.x;
    int v = (t < nb) ? partials[t] : 0;
    sm[t] = v;
    __syncthreads();
    for (int off = 1; off < 256; off <<= 1) {
        int add = (t >= off) ? sm[t - off] : 0;
        __syncthreads();
        sm[t] += add;
        __syncthreads();
    }
    if (t < nb) partials[t] = sm[t] - v;  // exclusive block offsets
    if (t == 0) start[N] = E;
}

__global__ __launch_bounds__(256) void scan3_k(int* __restrict__ start, int N, const int* __restrict__ partials) {
    int i = blockIdx.x * 256 + threadIdx.x;
    if (i < N) start[i] += partials[blockIdx.x];
}

__global__ __launch_bounds__(256) void fill_k(const int* __restrict__ src, const int* __restrict__ dst, int E,
                                              const int* __restrict__ start, int* __restrict__ cursor,
                                              int* __restrict__ eid, int* __restrict__ esrc) {
    int e = blockIdx.x * 256 + threadIdx.x;
    if (e < E) {
        int dd = dst[e];
        int pos = atomicAdd(&cursor[dd], 1);
        int i = start[dd] + pos;
        eid[i] = e;
        esrc[i] = src[e];
    }
}

// ---------------- fused QKVS GEMM (fp32 vector ALU) ----------------
// out[n, c] for Q/K/V/S: 16 nodes x 512 cols per block of 256 threads.
// Thread t: cols (t) of {Q or K} and (t&127) of {V or S}.

__global__ __launch_bounds__(256) void gemm_qkvs(
    const float* __restrict__ x,
    const float* __restrict__ Wq, const float* __restrict__ Wk,
    const float* __restrict__ Wv, const float* __restrict__ Ws,
    const float* __restrict__ bq, const float* __restrict__ bk,
    const float* __restrict__ bv, const float* __restrict__ bs,
    float* __restrict__ Q, float* __restrict__ K2,
    float* __restrict__ V, float* __restrict__ S, int N) {
    __shared__ float xs[16][F];
    int t = threadIdx.x;
    int n0 = blockIdx.x * 16;

    // stage 16 rows of x into LDS (512 float4, 2 per thread)
    {
        const float4* xg = (const float4*)(x + (size_t)n0 * F);
        float4* xl = (float4*)&xs[0][0];
        int i0 = t, i1 = t + 256;
        // guard for ragged last tile (N=50000 is divisible by 16, but be safe)
        int r0 = i0 >> 5, r1 = i1 >> 5;
        float4 z = {0.f, 0.f, 0.f, 0.f};
        xl[i0] = (n0 + r0 < N) ? xg[i0] : z;
        xl[i1] = (n0 + r1 < N) ? xg[i1] : z;
    }
    __syncthreads();

    int c = t & 127;
    bool lo = t < 128;
    const float* WA = lo ? (Wq + c) : (Wk + c);
    const float* WB = lo ? (Wv + c) : (Ws + c);

    float accA[16], accB[16];
#pragma unroll
    for (int n = 0; n < 16; n++) { accA[n] = 0.f; accB[n] = 0.f; }

    for (int i = 0; i < F; i += 4) {
        float a0 = WA[(i + 0) * F], a1 = WA[(i + 1) * F], a2 = WA[(i + 2) * F], a3 = WA[(i + 3) * F];
        float b0 = WB[(i + 0) * F], b1 = WB[(i + 1) * F], b2 = WB[(i + 2) * F], b3 = WB[(i + 3) * F];
#pragma unroll
        for (int n = 0; n < 16; n++) {
            float4 xv = *(const float4*)&xs[n][i];  // broadcast LDS read
            accA[n] += xv.x * a0 + xv.y * a1 + xv.z * a2 + xv.w * a3;
            accB[n] += xv.x * b0 + xv.y * b1 + xv.z * b2 + xv.w * b3;
        }
    }

    float bA = lo ? bq[c] : bk[c];
    float bB = lo ? bv[c] : bs[c];
    float* outA = lo ? Q : K2;
    float* outB = lo ? V : S;
#pragma unroll
    for (int n = 0; n < 16; n++) {
        if (n0 + n < N) {
            outA[(size_t)(n0 + n) * F + c] = accA[n] + bA;
            outB[(size_t)(n0 + n) * F + c] = accB[n] + bB;
        }
    }
}

// ---------------- fused edge kernel: one wave per destination node ----------------
// lane l owns features 2l, 2l+1  -> head = l>>3 (lanes 8h..8h+7 own head h).
// Pass A: alpha = (q.k)/4 via 8-lane butterfly; online softmax (m, d) in registers;
//         raw alpha stored to the output alpha slot (scratch).
// Pass B: a = exp(alpha - m)/d, write normalized alpha, accumulate a * v[src].
// Epilogue: out = acc + S[n] (+gelu for non-final layers).

__device__ __forceinline__ float gelu_exact(float v) {
    return 0.5f * v * (1.0f + erff(v * 0.70710678118654752f));
}

__global__ __launch_bounds__(256) void edge_k(
    const float* __restrict__ Q, const float* __restrict__ K,
    const float* __restrict__ V, const float* __restrict__ S,
    const int* __restrict__ start, const int* __restrict__ eid, const int* __restrict__ esrc,
    float* __restrict__ aout, float* __restrict__ hout, int N, int do_gelu) {
    int wave = (int)((blockIdx.x * (unsigned)blockDim.x + threadIdx.x) >> 6);
    int lane = threadIdx.x & 63;
    if (wave >= N) return;
    int n = wave;
    int beg = start[n], end = start[n + 1];
    int hsel = lane >> 3;

    float2 q = *(const float2*)&Q[(size_t)n * F + 2 * lane];

    float m = -INFINITY, d = 0.f;
    for (int i = beg; i < end; i++) {
        int e = eid[i];
        int s = esrc[i];
        float2 k = *(const float2*)&K[(size_t)s * F + 2 * lane];
        float p = q.x * k.x + q.y * k.y;
        p += __shfl_xor(p, 1);
        p += __shfl_xor(p, 2);
        p += __shfl_xor(p, 4);
        float alpha = p * 0.25f;  // 1/sqrt(16)
        if ((lane & 7) == 0) aout[(size_t)e * HEADS + hsel] = alpha;
        float mn = fmaxf(m, alpha);
        d = d * __expf(m - mn) + __expf(alpha - mn);
        m = mn;
    }
    __threadfence_block();  // make our alpha stores visible to our own re-reads (same CU L1)

    float inv_d = (d > 0.f) ? 1.f / d : 0.f;
    float2 acc = {0.f, 0.f};
    for (int i = beg; i < end; i++) {
        int e = eid[i];
        int s = esrc[i];
        float alpha = aout[(size_t)e * HEADS + hsel];
        float a = __expf(alpha - m) * inv_d;  // load->use dependency orders the store below after the read
        if ((lane & 7) == 0) aout[(size_t)e * HEADS + hsel] = a;
        float2 v = *(const float2*)&V[(size_t)s * F + 2 * lane];
        acc.x += a * v.x;
        acc.y += a * v.y;
    }

    float2 sv = *(const float2*)&S[(size_t)n * F + 2 * lane];
    float2 o = {acc.x + sv.x, acc.y + sv.y};
    if (do_gelu) {
        o.x = gelu_exact(o.x);
        o.y = gelu_exact(o.y);
    }
    *(float2*)&hout[(size_t)n * F + 2 * lane] = o;
}

// ---------------- launch ----------------

extern "C" void kernel_launch(void* const* d_in, const int* in_sizes, int n_in,
                              void* d_out, int out_size, void* d_ws, size_t ws_size,
                              hipStream_t stream) {
    const float* x  = (const float*)d_in[0];
    const int*   ei = (const int*)d_in[1];
    const float* Wq = (const float*)d_in[2];
    const float* bq = (const float*)d_in[3];
    const float* Wk = (const float*)d_in[4];
    const float* bk = (const float*)d_in[5];
    const float* Wv = (const float*)d_in[6];
    const float* bv = (const float*)d_in[7];
    const float* Ws = (const float*)d_in[8];
    const float* bs = (const float*)d_in[9];

    const int N = in_sizes[0] / F;
    const int E = in_sizes[1] / 2;
    const int L = in_sizes[2] / (F * F);

    // workspace layout (floats then ints)
    float* hbuf = (float*)d_ws;                    // N*F
    float* Qb = hbuf + (size_t)N * F;              // N*F
    float* Kb = Qb + (size_t)N * F;                // N*F
    float* Vb = Kb + (size_t)N * F;                // N*F
    float* Sb = Vb + (size_t)N * F;                // N*F
    int* start   = (int*)(Sb + (size_t)N * F);     // N+1
    int* cursor  = start + (N + 1);                // N
    int* eid     = cursor + N;                     // E
    int* esrc    = eid + E;                        // E
    int* partials = esrc + E;                      // <=256

    float* out_h = (float*)d_out;                  // N*F
    float* out_a = out_h + (size_t)N * F;          // L*E*H

    const int* srcIdx = ei;
    const int* dstIdx = ei + E;

    int nbScan = (N + 255) / 256;
    hipMemsetAsync(cursor, 0, sizeof(int) * N, stream);
    hist_k<<<(E + 255) / 256, 256, 0, stream>>>(dstIdx, E, cursor);
    scan1_k<<<nbScan, 256, 0, stream>>>(cursor, N, start, partials);
    scan2_k<<<1, 256, 0, stream>>>(partials, nbScan, start, N, E);
    scan3_k<<<nbScan, 256, 0, stream>>>(start, N, partials);
    hipMemsetAsync(cursor, 0, sizeof(int) * N, stream);
    fill_k<<<(E + 255) / 256, 256, 0, stream>>>(srcIdx, dstIdx, E, start, cursor, eid, esrc);

    for (int l = 0; l < L; ++l) {
        const float* hin = (l == 0) ? x : hbuf;
        gemm_qkvs<<<(N + 15) / 16, 256, 0, stream>>>(
            hin,
            Wq + (size_t)l * F * F, Wk + (size_t)l * F * F,
            Wv + (size_t)l * F * F, Ws + (size_t)l * F * F,
            bq + (size_t)l * F, bk + (size_t)l * F,
            bv + (size_t)l * F, bs + (size_t)l * F,
            Qb, Kb, Vb, Sb, N);
        float* hout = (l == L - 1) ? out_h : hbuf;
        edge_k<<<(N + 3) / 4, 256, 0, stream>>>(
            Qb, Kb, Vb, Sb, start, eid, esrc,
            out_a + (size_t)l * E * HEADS, hout, N, (l < L - 1) ? 1 : 0);
    }
}

// Round 2
// 1277.643 us; speedup vs baseline: 1.5973x; 1.5973x over previous
//
#include <hip/hip_runtime.h>
#include <math.h>

#define F 128
#define HEADS 8

typedef __attribute__((ext_vector_type(8))) short short8;
typedef __attribute__((ext_vector_type(4))) float floatx4;

__device__ __forceinline__ unsigned short f2bf(float f) {
    unsigned u = __float_as_uint(f);
    unsigned r = u + 0x7FFFu + ((u >> 16) & 1u);
    return (unsigned short)(r >> 16);
}
__device__ __forceinline__ float bf2f(unsigned short u) {
    return __uint_as_float(((unsigned)u) << 16);
}

// ---------------- CSR build ----------------

__global__ __launch_bounds__(256) void hist_k(const int* __restrict__ dst, int E, int* __restrict__ deg) {
    int e = blockIdx.x * 256 + threadIdx.x;
    if (e < E) atomicAdd(&deg[dst[e]], 1);
}

__global__ __launch_bounds__(256) void scan1_k(const int* __restrict__ deg, int N,
                                               int* __restrict__ start, int* __restrict__ partials) {
    __shared__ int sm[256];
    int t = threadIdx.x;
    int i = blockIdx.x * 256 + t;
    int v = (i < N) ? deg[i] : 0;
    sm[t] = v;
    __syncthreads();
    for (int off = 1; off < 256; off <<= 1) {
        int add = (t >= off) ? sm[t - off] : 0;
        __syncthreads();
        sm[t] += add;
        __syncthreads();
    }
    if (i < N) start[i] = sm[t] - v;
    if (t == 255) partials[blockIdx.x] = sm[t];
}

__global__ __launch_bounds__(256) void scan2_k(int* __restrict__ partials, int nb,
                                               int* __restrict__ start, int N, int E) {
    __shared__ int sm[256];
    int t = threadIdx.x;
    int v = (t < nb) ? partials[t] : 0;
    sm[t] = v;
    __syncthreads();
    for (int off = 1; off < 256; off <<= 1) {
        int add = (t >= off) ? sm[t - off] : 0;
        __syncthreads();
        sm[t] += add;
        __syncthreads();
    }
    if (t < nb) partials[t] = sm[t] - v;
    if (t == 0) start[N] = E;
}

__global__ __launch_bounds__(256) void scan3_k(int* __restrict__ start, int N, const int* __restrict__ partials) {
    int i = blockIdx.x * 256 + threadIdx.x;
    if (i < N) start[i] += partials[blockIdx.x];
}

__global__ __launch_bounds__(256) void fill_k(const int* __restrict__ src, const int* __restrict__ dst, int E,
                                              const int* __restrict__ start, int* __restrict__ cursor,
                                              int* __restrict__ eid, int* __restrict__ esrc) {
    int e = blockIdx.x * 256 + threadIdx.x;
    if (e < E) {
        int dd = dst[e];
        int pos = atomicAdd(&cursor[dd], 1);
        int i = start[dd] + pos;
        eid[i] = e;
        esrc[i] = src[e];
    }
}

// ---------------- weight pre-swizzle: fp32 W -> bf16 MFMA B-fragments ----------------
// Per matrix: frag index (((ntile*4 + chunk)*64 + lane)*8 + j) holds
// W[k][n] with k = chunk*32 + (lane>>4)*8 + j, n = ntile*16 + (lane&15).

__global__ __launch_bounds__(256) void wprep_k(
    const float* __restrict__ Wq, const float* __restrict__ Wk,
    const float* __restrict__ Wv, const float* __restrict__ Ws,
    unsigned short* __restrict__ out, int total) {
    int idx = blockIdx.x * 256 + threadIdx.x;
    if (idx >= total) return;
    int j = idx & 7;
    int lane = (idx >> 3) & 63;
    int rest = idx >> 9;
    int chunk = rest & 3;
    int ntile = (rest >> 2) & 7;
    int mat = (rest >> 5) & 3;
    int layer = rest >> 7;
    int k = chunk * 32 + (lane >> 4) * 8 + j;
    int n = ntile * 16 + (lane & 15);
    const float* W = (mat == 0) ? Wq : (mat == 1) ? Wk : (mat == 2) ? Wv : Ws;
    out[idx] = f2bf(W[((size_t)layer * F + k) * F + n]);
}

// ---------------- fused QKVS GEMM via bf16 MFMA ----------------
// Block = 4 waves; wave w computes matrix w (0:Q 1:K 2:V 3:S) for 32 rows.
// Per wave: 2 m-tiles x 8 n-tiles of 16x16, K=128 in 4 chunks of 32.
// A frags read directly from global fp32 x and packed to bf16.

__global__ __launch_bounds__(256) void gemm_mfma(
    const float* __restrict__ x, const unsigned short* __restrict__ wfrag,
    const float* __restrict__ bq, const float* __restrict__ bk,
    const float* __restrict__ bv, const float* __restrict__ bs,
    float* __restrict__ Q, unsigned short* __restrict__ K2,
    unsigned short* __restrict__ V, float* __restrict__ S, int N) {
    int wave = threadIdx.x >> 6;
    int lane = threadIdx.x & 63;
    int row0 = blockIdx.x * 32;
    int lm = lane & 15, quad = lane >> 4;
    const unsigned short* wf = wfrag + wave * 16384;

    floatx4 acc[2][8];
#pragma unroll
    for (int t = 0; t < 2; t++)
#pragma unroll
        for (int u = 0; u < 8; u++) acc[t][u] = (floatx4){0.f, 0.f, 0.f, 0.f};

#pragma unroll
    for (int chunk = 0; chunk < 4; chunk++) {
        short8 afr[2];
#pragma unroll
        for (int t = 0; t < 2; t++) {
            int m = row0 + t * 16 + lm;
            m = (m < N) ? m : (N - 1);
            const float* ap = x + (size_t)m * F + chunk * 32 + quad * 8;
            float4 f0 = *(const float4*)ap;
            float4 f1 = *(const float4*)(ap + 4);
            short8 a;
            a[0] = (short)f2bf(f0.x); a[1] = (short)f2bf(f0.y);
            a[2] = (short)f2bf(f0.z); a[3] = (short)f2bf(f0.w);
            a[4] = (short)f2bf(f1.x); a[5] = (short)f2bf(f1.y);
            a[6] = (short)f2bf(f1.z); a[7] = (short)f2bf(f1.w);
            afr[t] = a;
        }
#pragma unroll
        for (int u = 0; u < 8; u++) {
            short8 bfr = *(const short8*)(wf + ((u * 4 + chunk) * 64 + lane) * 8);
            acc[0][u] = __builtin_amdgcn_mfma_f32_16x16x32_bf16(afr[0], bfr, acc[0][u], 0, 0, 0);
            acc[1][u] = __builtin_amdgcn_mfma_f32_16x16x32_bf16(afr[1], bfr, acc[1][u], 0, 0, 0);
        }
    }

    const float* bias = (wave == 0) ? bq : (wave == 1) ? bk : (wave == 2) ? bv : bs;
#pragma unroll
    for (int u = 0; u < 8; u++) {
        int n = u * 16 + lm;
        float bn = bias[n];
#pragma unroll
        for (int t = 0; t < 2; t++) {
#pragma unroll
            for (int r = 0; r < 4; r++) {
                int m = row0 + t * 16 + quad * 4 + r;
                if (m < N) {
                    float val = acc[t][u][r] + bn;
                    size_t off = (size_t)m * F + n;
                    if (wave == 0) Q[off] = val;
                    else if (wave == 1) K2[off] = f2bf(val);
                    else if (wave == 2) V[off] = f2bf(val);
                    else S[off] = val;
                }
            }
        }
    }
}

// ---------------- fused edge kernel: one wave per destination node, single pass ----------------
// lane l owns features 2l,2l+1 -> head h = l>>3. Unnormalized softmax:
// w = exp(alpha); d += w; acc += w*v. Raw w stored to alpha output; flat
// normalize kernel multiplies by inv_d afterwards.

__device__ __forceinline__ float gelu_exact(float v) {
    return 0.5f * v * (1.0f + erff(v * 0.70710678118654752f));
}

__global__ __launch_bounds__(256) void edge_k(
    const float* __restrict__ Q, const unsigned short* __restrict__ K,
    const unsigned short* __restrict__ V, const float* __restrict__ S,
    const int* __restrict__ start, const int* __restrict__ eid, const int* __restrict__ esrc,
    float* __restrict__ aout, float* __restrict__ md,
    float* __restrict__ hout, int N, int do_gelu) {
    int wave = (int)((blockIdx.x * (unsigned)blockDim.x + threadIdx.x) >> 6);
    int lane = threadIdx.x & 63;
    if (wave >= N) return;
    int n = wave;
    int beg = start[n], end = start[n + 1];
    int hsel = lane >> 3;

    float2 q = *(const float2*)&Q[(size_t)n * F + 2 * lane];

    float d = 0.f;
    float2 acc = {0.f, 0.f};
    for (int i = beg; i < end; i++) {
        int e = eid[i];
        int s = esrc[i];
        ushort2 kb = *(const ushort2*)&K[(size_t)s * F + 2 * lane];
        ushort2 vb = *(const ushort2*)&V[(size_t)s * F + 2 * lane];
        float kx = bf2f(kb.x), ky = bf2f(kb.y);
        float vx = bf2f(vb.x), vy = bf2f(vb.y);
        float p = q.x * kx + q.y * ky;
        p += __shfl_xor(p, 1);
        p += __shfl_xor(p, 2);
        p += __shfl_xor(p, 4);
        float w = __expf(p * 0.25f);  // 1/sqrt(16)
        if ((lane & 7) == 0) aout[(size_t)e * HEADS + hsel] = w;
        d += w;
        acc.x += w * vx;
        acc.y += w * vy;
    }

    float inv_d = (d > 0.f) ? 1.f / d : 0.f;
    if ((lane & 7) == 0) md[(size_t)n * HEADS + hsel] = inv_d;

    float2 sv = *(const float2*)&S[(size_t)n * F + 2 * lane];
    float2 o = {acc.x * inv_d + sv.x, acc.y * inv_d + sv.y};
    if (do_gelu) {
        o.x = gelu_exact(o.x);
        o.y = gelu_exact(o.y);
    }
    *(float2*)&hout[(size_t)n * F + 2 * lane] = o;
}

// ---------------- flat alpha normalize ----------------

__global__ __launch_bounds__(256) void norm_k(float* __restrict__ a, const float* __restrict__ md,
                                              const int* __restrict__ dst, int E8) {
    int i = blockIdx.x * 256 + threadIdx.x;
    if (i < E8) {
        int e = i >> 3;
        int h = i & 7;
        a[i] *= md[(size_t)dst[e] * HEADS + h];
    }
}

// ---------------- launch ----------------

extern "C" void kernel_launch(void* const* d_in, const int* in_sizes, int n_in,
                              void* d_out, int out_size, void* d_ws, size_t ws_size,
                              hipStream_t stream) {
    const float* x  = (const float*)d_in[0];
    const int*   ei = (const int*)d_in[1];
    const float* Wq = (const float*)d_in[2];
    const float* bq = (const float*)d_in[3];
    const float* Wk = (const float*)d_in[4];
    const float* bk = (const float*)d_in[5];
    const float* Wv = (const float*)d_in[6];
    const float* bv = (const float*)d_in[7];
    const float* Ws = (const float*)d_in[8];
    const float* bs = (const float*)d_in[9];

    const int N = in_sizes[0] / F;
    const int E = in_sizes[1] / 2;
    const int L = in_sizes[2] / (F * F);

    // workspace layout
    float* hbuf = (float*)d_ws;                        // N*F fp32
    float* Qb = hbuf + (size_t)N * F;                  // N*F fp32
    float* Sb = Qb + (size_t)N * F;                    // N*F fp32
    float* md = Sb + (size_t)N * F;                    // N*HEADS fp32
    unsigned short* Kb = (unsigned short*)(md + (size_t)N * HEADS);  // N*F bf16
    unsigned short* Vb = Kb + (size_t)N * F;           // N*F bf16
    unsigned short* wfrag = Vb + (size_t)N * F;        // L*4*16384 bf16
    int* start = (int*)(wfrag + (size_t)L * 4 * 16384);  // N+1
    int* cursor = start + (N + 1);                     // N
    int* eid = cursor + N;                             // E
    int* esrc = eid + E;                               // E
    int* partials = esrc + E;                          // <=256

    float* out_h = (float*)d_out;                      // N*F
    float* out_a = out_h + (size_t)N * F;              // L*E*HEADS

    const int* srcIdx = ei;
    const int* dstIdx = ei + E;

    int nbScan = (N + 255) / 256;
    hipMemsetAsync(cursor, 0, sizeof(int) * N, stream);
    hist_k<<<(E + 255) / 256, 256, 0, stream>>>(dstIdx, E, cursor);
    scan1_k<<<nbScan, 256, 0, stream>>>(cursor, N, start, partials);
    scan2_k<<<1, 256, 0, stream>>>(partials, nbScan, start, N, E);
    scan3_k<<<nbScan, 256, 0, stream>>>(start, N, partials);
    hipMemsetAsync(cursor, 0, sizeof(int) * N, stream);
    fill_k<<<(E + 255) / 256, 256, 0, stream>>>(srcIdx, dstIdx, E, start, cursor, eid, esrc);

    int wtotal = L * 4 * 16384;
    wprep_k<<<(wtotal + 255) / 256, 256, 0, stream>>>(Wq, Wk, Wv, Ws, wfrag, wtotal);

    for (int l = 0; l < L; ++l) {
        const float* hin = (l == 0) ? x : hbuf;
        gemm_mfma<<<(N + 31) / 32, 256, 0, stream>>>(
            hin, wfrag + (size_t)l * 4 * 16384,
            bq + (size_t)l * F, bk + (size_t)l * F,
            bv + (size_t)l * F, bs + (size_t)l * F,
            Qb, Kb, Vb, Sb, N);
        float* hout = (l == L - 1) ? out_h : hbuf;
        edge_k<<<(N + 3) / 4, 256, 0, stream>>>(
            Qb, Kb, Vb, Sb, start, eid, esrc,
            out_a + (size_t)l * E * HEADS, md, hout, N, (l < L - 1) ? 1 : 0);
        norm_k<<<((E * HEADS) + 255) / 256, 256, 0, stream>>>(
            out_a + (size_t)l * E * HEADS, md, dstIdx, E * HEADS);
    }
}

// Round 3
// 945.859 us; speedup vs baseline: 2.1576x; 1.3508x over previous
//
#include <hip/hip_runtime.h>
#include <math.h>

#define F 128
#define HEADS 8

typedef __attribute__((ext_vector_type(8))) short short8;
typedef __attribute__((ext_vector_type(4))) float floatx4;

__device__ __forceinline__ unsigned short f2bf(float f) {
    unsigned u = __float_as_uint(f);
    unsigned r = u + 0x7FFFu + ((u >> 16) & 1u);
    return (unsigned short)(r >> 16);
}
__device__ __forceinline__ float bf2f(unsigned short u) {
    return __uint_as_float(((unsigned)u) << 16);
}

// ---------------- CSR build ----------------

__global__ __launch_bounds__(256) void hist_k(const int* __restrict__ dst, int E, int* __restrict__ deg) {
    int e = blockIdx.x * 256 + threadIdx.x;
    if (e < E) atomicAdd(&deg[dst[e]], 1);
}

__global__ __launch_bounds__(256) void scan1_k(const int* __restrict__ deg, int N,
                                               int* __restrict__ start, int* __restrict__ partials) {
    __shared__ int sm[256];
    int t = threadIdx.x;
    int i = blockIdx.x * 256 + t;
    int v = (i < N) ? deg[i] : 0;
    sm[t] = v;
    __syncthreads();
    for (int off = 1; off < 256; off <<= 1) {
        int add = (t >= off) ? sm[t - off] : 0;
        __syncthreads();
        sm[t] += add;
        __syncthreads();
    }
    if (i < N) start[i] = sm[t] - v;
    if (t == 255) partials[blockIdx.x] = sm[t];
}

__global__ __launch_bounds__(256) void scan2_k(int* __restrict__ partials, int nb,
                                               int* __restrict__ start, int N, int E) {
    __shared__ int sm[256];
    int t = threadIdx.x;
    int v = (t < nb) ? partials[t] : 0;
    sm[t] = v;
    __syncthreads();
    for (int off = 1; off < 256; off <<= 1) {
        int add = (t >= off) ? sm[t - off] : 0;
        __syncthreads();
        sm[t] += add;
        __syncthreads();
    }
    if (t < nb) partials[t] = sm[t] - v;
    if (t == 0) start[N] = E;
}

__global__ __launch_bounds__(256) void scan3_k(int* __restrict__ start, int N, const int* __restrict__ partials) {
    int i = blockIdx.x * 256 + threadIdx.x;
    if (i < N) start[i] += partials[blockIdx.x];
}

// epair[i] = (edge_id, src)
__global__ __launch_bounds__(256) void fill_k(const int* __restrict__ src, const int* __restrict__ dst, int E,
                                              const int* __restrict__ start, int* __restrict__ cursor,
                                              int2* __restrict__ epair) {
    int e = blockIdx.x * 256 + threadIdx.x;
    if (e < E) {
        int dd = dst[e];
        int pos = atomicAdd(&cursor[dd], 1);
        epair[start[dd] + pos] = make_int2(e, src[e]);
    }
}

// ---------------- x -> bf16 ----------------
__global__ __launch_bounds__(256) void cvt_k(const float* __restrict__ x, unsigned short* __restrict__ xb, int total4) {
    int i = blockIdx.x * 256 + threadIdx.x;
    if (i < total4) {
        float4 v = ((const float4*)x)[i];
        ushort4 o;
        o.x = f2bf(v.x); o.y = f2bf(v.y); o.z = f2bf(v.z); o.w = f2bf(v.w);
        ((ushort4*)xb)[i] = o;
    }
}

// ---------------- weight pre-swizzle: fp32 W -> bf16 MFMA B-fragments ----------------

__global__ __launch_bounds__(256) void wprep_k(
    const float* __restrict__ Wq, const float* __restrict__ Wk,
    const float* __restrict__ Wv, const float* __restrict__ Ws,
    unsigned short* __restrict__ out, int total) {
    int idx = blockIdx.x * 256 + threadIdx.x;
    if (idx >= total) return;
    int j = idx & 7;
    int lane = (idx >> 3) & 63;
    int rest = idx >> 9;
    int chunk = rest & 3;
    int ntile = (rest >> 2) & 7;
    int mat = (rest >> 5) & 3;
    int layer = rest >> 7;
    int k = chunk * 32 + (lane >> 4) * 8 + j;
    int n = ntile * 16 + (lane & 15);
    const float* W = (mat == 0) ? Wq : (mat == 1) ? Wk : (mat == 2) ? Wv : Ws;
    out[idx] = f2bf(W[((size_t)layer * F + k) * F + n]);
}

// ---------------- fused QKVS GEMM via bf16 MFMA ----------------
// Block = 4 waves; wave w computes matrix w (0:Q 1:K 2:V 3:S) for 32 rows.
// A frags read directly as bf16 short8 (no conversion).
// K/V written interleaved into kv[n][lane] = {k2l,k2l+1,v2l,v2l+1}.

__global__ __launch_bounds__(256) void gemm_mfma(
    const unsigned short* __restrict__ xb, const unsigned short* __restrict__ wfrag,
    const float* __restrict__ bq, const float* __restrict__ bk,
    const float* __restrict__ bv, const float* __restrict__ bs,
    float* __restrict__ Q, unsigned short* __restrict__ kvb,
    float* __restrict__ S, int N) {
    int wave = threadIdx.x >> 6;
    int lane = threadIdx.x & 63;
    int row0 = blockIdx.x * 32;
    int lm = lane & 15, quad = lane >> 4;
    const unsigned short* wf = wfrag + wave * 16384;

    floatx4 acc[2][8];
#pragma unroll
    for (int t = 0; t < 2; t++)
#pragma unroll
        for (int u = 0; u < 8; u++) acc[t][u] = (floatx4){0.f, 0.f, 0.f, 0.f};

#pragma unroll
    for (int chunk = 0; chunk < 4; chunk++) {
        short8 afr[2];
#pragma unroll
        for (int t = 0; t < 2; t++) {
            int m = row0 + t * 16 + lm;
            m = (m < N) ? m : (N - 1);
            afr[t] = *(const short8*)(xb + (size_t)m * F + chunk * 32 + quad * 8);
        }
#pragma unroll
        for (int u = 0; u < 8; u++) {
            short8 bfr = *(const short8*)(wf + ((u * 4 + chunk) * 64 + lane) * 8);
            acc[0][u] = __builtin_amdgcn_mfma_f32_16x16x32_bf16(afr[0], bfr, acc[0][u], 0, 0, 0);
            acc[1][u] = __builtin_amdgcn_mfma_f32_16x16x32_bf16(afr[1], bfr, acc[1][u], 0, 0, 0);
        }
    }

    const float* bias = (wave == 0) ? bq : (wave == 1) ? bk : (wave == 2) ? bv : bs;
#pragma unroll
    for (int u = 0; u < 8; u++) {
        int n = u * 16 + lm;
        float bn = bias[n];
#pragma unroll
        for (int t = 0; t < 2; t++) {
#pragma unroll
            for (int r = 0; r < 4; r++) {
                int m = row0 + t * 16 + quad * 4 + r;
                if (m < N) {
                    float val = acc[t][u][r] + bn;
                    if (wave == 0) Q[(size_t)m * F + n] = val;
                    else if (wave == 1) kvb[(size_t)m * 2 * F + (n >> 1) * 4 + (n & 1)] = f2bf(val);
                    else if (wave == 2) kvb[(size_t)m * 2 * F + (n >> 1) * 4 + 2 + (n & 1)] = f2bf(val);
                    else S[(size_t)m * F + n] = val;
                }
            }
        }
    }
}

// ---------------- fused edge kernel: one wave per destination node, single pass ----------------
// lane l owns features 2l,2l+1 -> head h = l>>3. Unnormalized softmax,
// unrolled by 4 for memory-level parallelism.

__device__ __forceinline__ float gelu_exact(float v) {
    return 0.5f * v * (1.0f + erff(v * 0.70710678118654752f));
}

__global__ __launch_bounds__(256) void edge_k(
    const float* __restrict__ Q, const unsigned short* __restrict__ kvb,
    const float* __restrict__ S,
    const int* __restrict__ start, const int2* __restrict__ epair,
    float* __restrict__ aout, float* __restrict__ md,
    float* __restrict__ hout_f, unsigned short* __restrict__ hout_b,
    int N, int do_gelu) {
    int wave = (int)((blockIdx.x * (unsigned)blockDim.x + threadIdx.x) >> 6);
    int lane = threadIdx.x & 63;
    if (wave >= N) return;
    int n = wave;
    int beg = start[n], end = start[n + 1];
    int hsel = lane >> 3;

    float2 q = *(const float2*)&Q[(size_t)n * F + 2 * lane];

    float d = 0.f;
    float2 acc = {0.f, 0.f};

    auto step = [&](int e, ushort4 kv) {
        float kx = bf2f(kv.x), ky = bf2f(kv.y);
        float vx = bf2f(kv.z), vy = bf2f(kv.w);
        float p = q.x * kx + q.y * ky;
        p += __shfl_xor(p, 1);
        p += __shfl_xor(p, 2);
        p += __shfl_xor(p, 4);
        float w = __expf(p * 0.25f);  // 1/sqrt(16)
        if ((lane & 7) == 0) aout[(size_t)e * HEADS + hsel] = w;
        d += w;
        acc.x += w * vx;
        acc.y += w * vy;
    };

    int i = beg;
    for (; i + 4 <= end; i += 4) {
        int2 p0 = epair[i], p1 = epair[i + 1], p2 = epair[i + 2], p3 = epair[i + 3];
        ushort4 kv0 = *(const ushort4*)&kvb[(size_t)p0.y * 2 * F + lane * 4];
        ushort4 kv1 = *(const ushort4*)&kvb[(size_t)p1.y * 2 * F + lane * 4];
        ushort4 kv2 = *(const ushort4*)&kvb[(size_t)p2.y * 2 * F + lane * 4];
        ushort4 kv3 = *(const ushort4*)&kvb[(size_t)p3.y * 2 * F + lane * 4];
        step(p0.x, kv0);
        step(p1.x, kv1);
        step(p2.x, kv2);
        step(p3.x, kv3);
    }
    for (; i < end; i++) {
        int2 p = epair[i];
        ushort4 kv = *(const ushort4*)&kvb[(size_t)p.y * 2 * F + lane * 4];
        step(p.x, kv);
    }

    float inv_d = (d > 0.f) ? 1.f / d : 0.f;
    if ((lane & 7) == 0) md[(size_t)n * HEADS + hsel] = inv_d;

    float2 sv = *(const float2*)&S[(size_t)n * F + 2 * lane];
    float2 o = {acc.x * inv_d + sv.x, acc.y * inv_d + sv.y};
    if (do_gelu) {
        o.x = gelu_exact(o.x);
        o.y = gelu_exact(o.y);
        ushort2 ob;
        ob.x = f2bf(o.x);
        ob.y = f2bf(o.y);
        *(ushort2*)&hout_b[(size_t)n * F + 2 * lane] = ob;
    } else {
        *(float2*)&hout_f[(size_t)n * F + 2 * lane] = o;
    }
}

// ---------------- flat alpha normalize ----------------

__global__ __launch_bounds__(256) void norm_k(float* __restrict__ a, const float* __restrict__ md,
                                              const int* __restrict__ dst, int E8) {
    int i = blockIdx.x * 256 + threadIdx.x;
    if (i < E8) {
        int e = i >> 3;
        int h = i & 7;
        a[i] *= md[(size_t)dst[e] * HEADS + h];
    }
}

// ---------------- launch ----------------

extern "C" void kernel_launch(void* const* d_in, const int* in_sizes, int n_in,
                              void* d_out, int out_size, void* d_ws, size_t ws_size,
                              hipStream_t stream) {
    const float* x  = (const float*)d_in[0];
    const int*   ei = (const int*)d_in[1];
    const float* Wq = (const float*)d_in[2];
    const float* bq = (const float*)d_in[3];
    const float* Wk = (const float*)d_in[4];
    const float* bk = (const float*)d_in[5];
    const float* Wv = (const float*)d_in[6];
    const float* bv = (const float*)d_in[7];
    const float* Ws = (const float*)d_in[8];
    const float* bs = (const float*)d_in[9];

    const int N = in_sizes[0] / F;
    const int E = in_sizes[1] / 2;
    const int L = in_sizes[2] / (F * F);

    // workspace layout
    float* Qb = (float*)d_ws;                             // N*F fp32
    float* Sb = Qb + (size_t)N * F;                       // N*F fp32
    float* md = Sb + (size_t)N * F;                       // N*HEADS fp32
    unsigned short* xb = (unsigned short*)(md + (size_t)N * HEADS);  // N*F bf16 (layer-0 input)
    unsigned short* hb = xb + (size_t)N * F;              // N*F bf16 (inter-layer h)
    unsigned short* kvb = hb + (size_t)N * F;             // N*2F bf16 interleaved K/V
    unsigned short* wfrag = kvb + (size_t)N * 2 * F;      // L*4*16384 bf16
    int* start = (int*)(wfrag + (size_t)L * 4 * 16384);   // N+1
    int* cursor = start + (N + 1);                        // N
    int2* epair = (int2*)(cursor + N);                    // E int2
    int* partials = (int*)(epair + E);                    // <=256

    float* out_h = (float*)d_out;                         // N*F
    float* out_a = out_h + (size_t)N * F;                 // L*E*HEADS

    const int* srcIdx = ei;
    const int* dstIdx = ei + E;

    int nbScan = (N + 255) / 256;
    hipMemsetAsync(cursor, 0, sizeof(int) * N, stream);
    hist_k<<<(E + 255) / 256, 256, 0, stream>>>(dstIdx, E, cursor);
    scan1_k<<<nbScan, 256, 0, stream>>>(cursor, N, start, partials);
    scan2_k<<<1, 256, 0, stream>>>(partials, nbScan, start, N, E);
    scan3_k<<<nbScan, 256, 0, stream>>>(start, N, partials);
    hipMemsetAsync(cursor, 0, sizeof(int) * N, stream);
    fill_k<<<(E + 255) / 256, 256, 0, stream>>>(srcIdx, dstIdx, E, start, cursor, epair);

    int wtotal = L * 4 * 16384;
    wprep_k<<<(wtotal + 255) / 256, 256, 0, stream>>>(Wq, Wk, Wv, Ws, wfrag, wtotal);
    cvt_k<<<((N * F / 4) + 255) / 256, 256, 0, stream>>>(x, xb, N * F / 4);

    for (int l = 0; l < L; ++l) {
        const unsigned short* hin = (l == 0) ? xb : hb;
        gemm_mfma<<<(N + 31) / 32, 256, 0, stream>>>(
            hin, wfrag + (size_t)l * 4 * 16384,
            bq + (size_t)l * F, bk + (size_t)l * F,
            bv + (size_t)l * F, bs + (size_t)l * F,
            Qb, kvb, Sb, N);
        edge_k<<<(N + 3) / 4, 256, 0, stream>>>(
            Qb, kvb, Sb, start, epair,
            out_a + (size_t)l * E * HEADS, md, out_h, hb, N, (l < L - 1) ? 1 : 0);
        norm_k<<<((E * HEADS) + 255) / 256, 256, 0, stream>>>(
            out_a + (size_t)l * E * HEADS, md, dstIdx, E * HEADS);
    }
}

// Round 4
// 797.671 us; speedup vs baseline: 2.5584x; 1.1858x over previous
//
#include <hip/hip_runtime.h>
#include <math.h>

#define F 128
#define HEADS 8

typedef __attribute__((ext_vector_type(8))) short short8;
typedef __attribute__((ext_vector_type(4))) float floatx4;

__device__ __forceinline__ unsigned short f2bf(float f) {
    unsigned u = __float_as_uint(f);
    unsigned r = u + 0x7FFFu + ((u >> 16) & 1u);
    return (unsigned short)(r >> 16);
}
__device__ __forceinline__ float bf2f(unsigned short u) {
    return __uint_as_float(((unsigned)u) << 16);
}
__device__ __forceinline__ float bflo(unsigned u) { return __uint_as_float(u << 16); }
__device__ __forceinline__ float bfhi(unsigned u) { return __uint_as_float(u & 0xffff0000u); }

// ---------------- CSR build ----------------

__global__ __launch_bounds__(256) void hist_k(const int* __restrict__ dst, int E, int* __restrict__ deg) {
    int e = blockIdx.x * 256 + threadIdx.x;
    if (e < E) atomicAdd(&deg[dst[e]], 1);
}

__global__ __launch_bounds__(256) void scan1_k(const int* __restrict__ deg, int N,
                                               int* __restrict__ start, int* __restrict__ partials) {
    __shared__ int sm[256];
    int t = threadIdx.x;
    int i = blockIdx.x * 256 + t;
    int v = (i < N) ? deg[i] : 0;
    sm[t] = v;
    __syncthreads();
    for (int off = 1; off < 256; off <<= 1) {
        int add = (t >= off) ? sm[t - off] : 0;
        __syncthreads();
        sm[t] += add;
        __syncthreads();
    }
    if (i < N) start[i] = sm[t] - v;
    if (t == 255) partials[blockIdx.x] = sm[t];
}

__global__ __launch_bounds__(256) void scan2_k(int* __restrict__ partials, int nb,
                                               int* __restrict__ start, int N, int E) {
    __shared__ int sm[256];
    int t = threadIdx.x;
    int v = (t < nb) ? partials[t] : 0;
    sm[t] = v;
    __syncthreads();
    for (int off = 1; off < 256; off <<= 1) {
        int add = (t >= off) ? sm[t - off] : 0;
        __syncthreads();
        sm[t] += add;
        __syncthreads();
    }
    if (t < nb) partials[t] = sm[t] - v;
    if (t == 0) start[N] = E;
}

__global__ __launch_bounds__(256) void scan3_k(int* __restrict__ start, int N, const int* __restrict__ partials) {
    int i = blockIdx.x * 256 + threadIdx.x;
    if (i < N) start[i] += partials[blockIdx.x];
}

// epair[i] = (edge_id, src)
__global__ __launch_bounds__(256) void fill_k(const int* __restrict__ src, const int* __restrict__ dst, int E,
                                              const int* __restrict__ start, int* __restrict__ cursor,
                                              int2* __restrict__ epair) {
    int e = blockIdx.x * 256 + threadIdx.x;
    if (e < E) {
        int dd = dst[e];
        int pos = atomicAdd(&cursor[dd], 1);
        epair[start[dd] + pos] = make_int2(e, src[e]);
    }
}

// ---------------- x -> bf16 ----------------
__global__ __launch_bounds__(256) void cvt_k(const float* __restrict__ x, unsigned short* __restrict__ xb, int total4) {
    int i = blockIdx.x * 256 + threadIdx.x;
    if (i < total4) {
        float4 v = ((const float4*)x)[i];
        ushort4 o;
        o.x = f2bf(v.x); o.y = f2bf(v.y); o.z = f2bf(v.z); o.w = f2bf(v.w);
        ((ushort4*)xb)[i] = o;
    }
}

// ---------------- weight pre-swizzle: fp32 W -> bf16 MFMA A-fragments ----------------
// frag holds W[k][f] at A[m=lane&15 -> f_local][k=quad*8+j] (A/B frag layouts are symmetric)

__global__ __launch_bounds__(256) void wprep_k(
    const float* __restrict__ Wq, const float* __restrict__ Wk,
    const float* __restrict__ Wv, const float* __restrict__ Ws,
    unsigned short* __restrict__ out, int total) {
    int idx = blockIdx.x * 256 + threadIdx.x;
    if (idx >= total) return;
    int j = idx & 7;
    int lane = (idx >> 3) & 63;
    int rest = idx >> 9;
    int chunk = rest & 3;
    int ftile = (rest >> 2) & 7;
    int mat = (rest >> 5) & 3;
    int layer = rest >> 7;
    int k = chunk * 32 + (lane >> 4) * 8 + j;
    int f = ftile * 16 + (lane & 15);
    const float* W = (mat == 0) ? Wq : (mat == 1) ? Wk : (mat == 2) ? Wv : Ws;
    out[idx] = f2bf(W[((size_t)layer * F + k) * F + f]);
}

// ---------------- fused QKVS GEMM via bf16 MFMA (A=W^T frags, B=x rows) ----------------
// Block = 4 waves; wave w computes matrix w (0:Q 1:K 2:V 3:S) for 32 nodes (2 n-tiles).
// D[f][node]: col=lane&15 = node, row=quad*4+r = feature -> each lane stores
// 4 consecutive features per (t,u) as one vector store.

__global__ __launch_bounds__(256) void gemm_mfma(
    const unsigned short* __restrict__ xb, const unsigned short* __restrict__ wfrag,
    const float* __restrict__ bq, const float* __restrict__ bk,
    const float* __restrict__ bv, const float* __restrict__ bs,
    float* __restrict__ Q, unsigned short* __restrict__ Kb,
    unsigned short* __restrict__ Vb, float* __restrict__ S, int N) {
    int wave = threadIdx.x >> 6;
    int lane = threadIdx.x & 63;
    int row0 = blockIdx.x * 32;
    int lm = lane & 15, quad = lane >> 4;
    const unsigned short* wf = wfrag + wave * 16384;

    floatx4 acc[2][8];
#pragma unroll
    for (int t = 0; t < 2; t++)
#pragma unroll
        for (int u = 0; u < 8; u++) acc[t][u] = (floatx4){0.f, 0.f, 0.f, 0.f};

#pragma unroll
    for (int chunk = 0; chunk < 4; chunk++) {
        short8 xfr[2];
#pragma unroll
        for (int t = 0; t < 2; t++) {
            int m = row0 + t * 16 + lm;
            m = (m < N) ? m : (N - 1);
            xfr[t] = *(const short8*)(xb + (size_t)m * F + chunk * 32 + quad * 8);
        }
#pragma unroll
        for (int u = 0; u < 8; u++) {
            short8 wfr = *(const short8*)(wf + ((u * 4 + chunk) * 64 + lane) * 8);
            acc[0][u] = __builtin_amdgcn_mfma_f32_16x16x32_bf16(wfr, xfr[0], acc[0][u], 0, 0, 0);
            acc[1][u] = __builtin_amdgcn_mfma_f32_16x16x32_bf16(wfr, xfr[1], acc[1][u], 0, 0, 0);
        }
    }

    const float* bias = (wave == 0) ? bq : (wave == 1) ? bk : (wave == 2) ? bv : bs;
#pragma unroll
    for (int u = 0; u < 8; u++) {
        float4 bv4 = *(const float4*)&bias[u * 16 + quad * 4];
#pragma unroll
        for (int t = 0; t < 2; t++) {
            int node = row0 + t * 16 + lm;
            if (node < N) {
                floatx4 a = acc[t][u];
                size_t off = (size_t)node * F + u * 16 + quad * 4;
                float v0 = a[0] + bv4.x, v1 = a[1] + bv4.y, v2 = a[2] + bv4.z, v3 = a[3] + bv4.w;
                if (wave == 0) {
                    *(float4*)&Q[off] = make_float4(v0, v1, v2, v3);
                } else if (wave == 1) {
                    ushort4 o = {f2bf(v0), f2bf(v1), f2bf(v2), f2bf(v3)};
                    *(ushort4*)&Kb[off] = o;
                } else if (wave == 2) {
                    ushort4 o = {f2bf(v0), f2bf(v1), f2bf(v2), f2bf(v3)};
                    *(ushort4*)&Vb[off] = o;
                } else {
                    *(float4*)&S[off] = make_float4(v0, v1, v2, v3);
                }
            }
        }
    }
}

// ---------------- fused edge kernel: one wave per destination node ----------------
// Phase 1: lane=(slot=lane>>3, h=lane&7): full 16-dim dot in-lane, 8 edges/iter,
//          w=exp(alpha) -> LDS wbuf + coalesced aout store; per-lane partial d.
// Phase 2: lane=(g=lane>>4, fl=lane&15): V rows 16B/lane, 4 edges/iter,
//          w broadcast from LDS; xor-combine groups at the end.

__device__ __forceinline__ float gelu_exact(float v) {
    return 0.5f * v * (1.0f + erff(v * 0.70710678118654752f));
}

__global__ __launch_bounds__(256) void edge_k(
    const float* __restrict__ Q, const unsigned short* __restrict__ Kb,
    const unsigned short* __restrict__ Vb, const float* __restrict__ S,
    const int* __restrict__ start, const int2* __restrict__ epair,
    float* __restrict__ aout, float* __restrict__ md,
    float* __restrict__ hout_f, unsigned short* __restrict__ hout_b,
    int N, int do_gelu) {
    __shared__ float wbuf[4][64][8];
    __shared__ int sbuf[4][64];
    __shared__ float mdbuf[4][8];

    int wv = threadIdx.x >> 6;
    int lane = threadIdx.x & 63;
    int n = blockIdx.x * 4 + wv;
    if (n >= N) return;   // no block-level barriers below: safe

    int beg = start[n], end = start[n + 1];
    int slot = lane >> 3, h = lane & 7;
    int g = lane >> 4, fl = lane & 15;
    int fh = fl >> 1;

    // q for head h: 16 fp32
    const float* qp = Q + (size_t)n * F + h * 16;
    float4 q0 = *(const float4*)(qp + 0);
    float4 q1 = *(const float4*)(qp + 4);
    float4 q2 = *(const float4*)(qp + 8);
    float4 q3 = *(const float4*)(qp + 12);

    float d = 0.f;
    float a0 = 0.f, a1 = 0.f, a2 = 0.f, a3 = 0.f, a4 = 0.f, a5 = 0.f, a6 = 0.f, a7 = 0.f;

    for (int c0 = beg; c0 < end; c0 += 64) {
        int cnt = min(64, end - c0);

        // ---- phase 1: alpha / w ----
        int nit = (cnt + 7) >> 3;
        for (int it = 0; it < nit; it++) {
            int idx = it * 8 + slot;
            bool val = idx < cnt;
            int gi = c0 + (val ? idx : 0);
            int2 pe = epair[gi];
            int s = pe.y;
            const unsigned short* kp = Kb + (size_t)s * F + h * 16;
            uint4 ka = *(const uint4*)(kp);
            uint4 kc = *(const uint4*)(kp + 8);
            float p = q0.x * bflo(ka.x) + q0.y * bfhi(ka.x)
                    + q0.z * bflo(ka.y) + q0.w * bfhi(ka.y)
                    + q1.x * bflo(ka.z) + q1.y * bfhi(ka.z)
                    + q1.z * bflo(ka.w) + q1.w * bfhi(ka.w)
                    + q2.x * bflo(kc.x) + q2.y * bfhi(kc.x)
                    + q2.z * bflo(kc.y) + q2.w * bfhi(kc.y)
                    + q3.x * bflo(kc.z) + q3.y * bfhi(kc.z)
                    + q3.z * bflo(kc.w) + q3.w * bfhi(kc.w);
            float w = __expf(p * 0.25f);  // 1/sqrt(16)
            if (!val) w = 0.f;
            d += w;
            wbuf[wv][idx][h] = w;
            if (h == 0) sbuf[wv][idx] = s;
            if (val) aout[(size_t)pe.x * HEADS + h] = w;
        }

        // ---- phase 2: V accumulation ----
        for (int j = 0; j < cnt; j += 8) {
            int idx0 = j + g;
            int idx1 = j + 4 + g;
            bool v0 = idx0 < cnt;
            bool v1 = idx1 < cnt;
            int s0 = sbuf[wv][v0 ? idx0 : 0];
            int s1 = sbuf[wv][v1 ? idx1 : 0];
            float w0 = wbuf[wv][v0 ? idx0 : 0][fh];
            float w1 = wbuf[wv][v1 ? idx1 : 0][fh];
            if (!v0) w0 = 0.f;
            if (!v1) w1 = 0.f;
            uint4 va = *(const uint4*)&Vb[(size_t)s0 * F + fl * 8];
            uint4 vb2 = *(const uint4*)&Vb[(size_t)s1 * F + fl * 8];
            a0 += w0 * bflo(va.x); a1 += w0 * bfhi(va.x);
            a2 += w0 * bflo(va.y); a3 += w0 * bfhi(va.y);
            a4 += w0 * bflo(va.z); a5 += w0 * bfhi(va.z);
            a6 += w0 * bflo(va.w); a7 += w0 * bfhi(va.w);
            a0 += w1 * bflo(vb2.x); a1 += w1 * bfhi(vb2.x);
            a2 += w1 * bflo(vb2.y); a3 += w1 * bfhi(vb2.y);
            a4 += w1 * bflo(vb2.z); a5 += w1 * bfhi(vb2.z);
            a6 += w1 * bflo(vb2.w); a7 += w1 * bfhi(vb2.w);
        }
    }

    // reduce d over slots (lanes sharing h)
    d += __shfl_xor(d, 8);
    d += __shfl_xor(d, 16);
    d += __shfl_xor(d, 32);
    float inv_d = (d > 0.f) ? 1.f / d : 0.f;
    if (slot == 0) {
        md[(size_t)n * HEADS + h] = inv_d;
        mdbuf[wv][h] = inv_d;
    }

    // combine the 4 phase-2 groups
    a0 += __shfl_xor(a0, 16); a0 += __shfl_xor(a0, 32);
    a1 += __shfl_xor(a1, 16); a1 += __shfl_xor(a1, 32);
    a2 += __shfl_xor(a2, 16); a2 += __shfl_xor(a2, 32);
    a3 += __shfl_xor(a3, 16); a3 += __shfl_xor(a3, 32);
    a4 += __shfl_xor(a4, 16); a4 += __shfl_xor(a4, 32);
    a5 += __shfl_xor(a5, 16); a5 += __shfl_xor(a5, 32);
    a6 += __shfl_xor(a6, 16); a6 += __shfl_xor(a6, 32);
    a7 += __shfl_xor(a7, 16); a7 += __shfl_xor(a7, 32);

    if (lane < 16) {
        float invd = mdbuf[wv][fh];
        const float* sp = S + (size_t)n * F + fl * 8;
        float4 s0 = *(const float4*)(sp + 0);
        float4 s1 = *(const float4*)(sp + 4);
        float o0 = a0 * invd + s0.x, o1 = a1 * invd + s0.y;
        float o2 = a2 * invd + s0.z, o3 = a3 * invd + s0.w;
        float o4 = a4 * invd + s1.x, o5 = a5 * invd + s1.y;
        float o6 = a6 * invd + s1.z, o7 = a7 * invd + s1.w;
        if (do_gelu) {
            o0 = gelu_exact(o0); o1 = gelu_exact(o1); o2 = gelu_exact(o2); o3 = gelu_exact(o3);
            o4 = gelu_exact(o4); o5 = gelu_exact(o5); o6 = gelu_exact(o6); o7 = gelu_exact(o7);
            uint4 ob;
            ob.x = (unsigned)f2bf(o0) | ((unsigned)f2bf(o1) << 16);
            ob.y = (unsigned)f2bf(o2) | ((unsigned)f2bf(o3) << 16);
            ob.z = (unsigned)f2bf(o4) | ((unsigned)f2bf(o5) << 16);
            ob.w = (unsigned)f2bf(o6) | ((unsigned)f2bf(o7) << 16);
            *(uint4*)&hout_b[(size_t)n * F + fl * 8] = ob;
        } else {
            float* op = hout_f + (size_t)n * F + fl * 8;
            *(float4*)(op + 0) = make_float4(o0, o1, o2, o3);
            *(float4*)(op + 4) = make_float4(o4, o5, o6, o7);
        }
    }
}

// ---------------- flat alpha normalize ----------------

__global__ __launch_bounds__(256) void norm_k(float* __restrict__ a, const float* __restrict__ md,
                                              const int* __restrict__ dst, int E8) {
    int i = blockIdx.x * 256 + threadIdx.x;
    if (i < E8) {
        int e = i >> 3;
        int h = i & 7;
        a[i] *= md[(size_t)dst[e] * HEADS + h];
    }
}

// ---------------- launch ----------------

extern "C" void kernel_launch(void* const* d_in, const int* in_sizes, int n_in,
                              void* d_out, int out_size, void* d_ws, size_t ws_size,
                              hipStream_t stream) {
    const float* x  = (const float*)d_in[0];
    const int*   ei = (const int*)d_in[1];
    const float* Wq = (const float*)d_in[2];
    const float* bq = (const float*)d_in[3];
    const float* Wk = (const float*)d_in[4];
    const float* bk = (const float*)d_in[5];
    const float* Wv = (const float*)d_in[6];
    const float* bv = (const float*)d_in[7];
    const float* Ws = (const float*)d_in[8];
    const float* bs = (const float*)d_in[9];

    const int N = in_sizes[0] / F;
    const int E = in_sizes[1] / 2;
    const int L = in_sizes[2] / (F * F);

    // workspace layout
    float* Qb = (float*)d_ws;                             // N*F fp32
    float* Sb = Qb + (size_t)N * F;                       // N*F fp32
    float* md = Sb + (size_t)N * F;                       // N*HEADS fp32
    unsigned short* xb = (unsigned short*)(md + (size_t)N * HEADS);  // N*F bf16
    unsigned short* hb = xb + (size_t)N * F;              // N*F bf16
    unsigned short* Kb = hb + (size_t)N * F;              // N*F bf16
    unsigned short* Vb = Kb + (size_t)N * F;              // N*F bf16
    unsigned short* wfrag = Vb + (size_t)N * F;           // L*4*16384 bf16
    int* start = (int*)(wfrag + (size_t)L * 4 * 16384);   // N+1
    int* cursor = start + (N + 1);                        // N
    int2* epair = (int2*)(cursor + N);                    // E int2
    int* partials = (int*)(epair + E);                    // <=256

    float* out_h = (float*)d_out;                         // N*F
    float* out_a = out_h + (size_t)N * F;                 // L*E*HEADS

    const int* srcIdx = ei;
    const int* dstIdx = ei + E;

    int nbScan = (N + 255) / 256;
    hipMemsetAsync(cursor, 0, sizeof(int) * N, stream);
    hist_k<<<(E + 255) / 256, 256, 0, stream>>>(dstIdx, E, cursor);
    scan1_k<<<nbScan, 256, 0, stream>>>(cursor, N, start, partials);
    scan2_k<<<1, 256, 0, stream>>>(partials, nbScan, start, N, E);
    scan3_k<<<nbScan, 256, 0, stream>>>(start, N, partials);
    hipMemsetAsync(cursor, 0, sizeof(int) * N, stream);
    fill_k<<<(E + 255) / 256, 256, 0, stream>>>(srcIdx, dstIdx, E, start, cursor, epair);

    int wtotal = L * 4 * 16384;
    wprep_k<<<(wtotal + 255) / 256, 256, 0, stream>>>(Wq, Wk, Wv, Ws, wfrag, wtotal);
    cvt_k<<<((N * F / 4) + 255) / 256, 256, 0, stream>>>(x, xb, N * F / 4);

    for (int l = 0; l < L; ++l) {
        const unsigned short* hin = (l == 0) ? xb : hb;
        gemm_mfma<<<(N + 31) / 32, 256, 0, stream>>>(
            hin, wfrag + (size_t)l * 4 * 16384,
            bq + (size_t)l * F, bk + (size_t)l * F,
            bv + (size_t)l * F, bs + (size_t)l * F,
            Qb, Kb, Vb, Sb, N);
        edge_k<<<(N + 3) / 4, 256, 0, stream>>>(
            Qb, Kb, Vb, Sb, start, epair,
            out_a + (size_t)l * E * HEADS, md, out_h, hb, N, (l < L - 1) ? 1 : 0);
        norm_k<<<((E * HEADS) + 255) / 256, 256, 0, stream>>>(
            out_a + (size_t)l * E * HEADS, md, dstIdx, E * HEADS);
    }
}